// Round 2
// baseline (2267.284 us; speedup 1.0000x reference)
//
#include <hip/hip_runtime.h>
#include <hip/hip_bf16.h>
#include <stdint.h>

#define TOK  8192
#define DIN  4096
#define DOUT 4096
#define NPL  3

typedef unsigned short u16;
typedef __attribute__((ext_vector_type(8))) __bf16 bf16x8;
typedef __attribute__((ext_vector_type(4))) float f32x4;
typedef __attribute__((ext_vector_type(4))) unsigned short u16x4;

// ADC_MUL = (0.6/127) * 8020 * 256
#define ADC_MUL   9699.7795275590551f
#define INV256    0.00390625f

#define GL(src, dst) __builtin_amdgcn_global_load_lds( \
    (const __attribute__((address_space(1))) void*)(src), \
    (__attribute__((address_space(3))) void*)(dst), 16, 0, 0)

// ---------------- Kernel 1: DAC  x (f32) -> k (bf16 integer levels) ----------------
__global__ void dac_kernel(const float* __restrict__ x, u16* __restrict__ a) {
    const int n4 = TOK * DIN / 4;
    int i = blockIdx.x * blockDim.x + threadIdx.x;
    const int stride = gridDim.x * blockDim.x;
    const float4* xv = (const float4*)x;
    u16x4* av = (u16x4*)a;
    for (; i < n4; i += stride) {
        float4 v = xv[i];
        u16x4 o;
        float t, k;
        t = v.x * 0.15f; t = fminf(1.0f, fmaxf(-1.0f, t)); k = rintf(t * 127.0f);
        o.x = (u16)(__float_as_uint(k) >> 16);
        t = v.y * 0.15f; t = fminf(1.0f, fmaxf(-1.0f, t)); k = rintf(t * 127.0f);
        o.y = (u16)(__float_as_uint(k) >> 16);
        t = v.z * 0.15f; t = fminf(1.0f, fmaxf(-1.0f, t)); k = rintf(t * 127.0f);
        o.z = (u16)(__float_as_uint(k) >> 16);
        t = v.w * 0.15f; t = fminf(1.0f, fmaxf(-1.0f, t)); k = rintf(t * 127.0f);
        o.w = (u16)(__float_as_uint(k) >> 16);
        av[i] = o;
    }
}

// ---------------- Kernel 2: w_eff -> hi/lo bf16, layout W[o][p][hi 4096 | lo 4096] ----
__global__ void wsplit_kernel(const float* __restrict__ wp, const float* __restrict__ wn,
                              u16* __restrict__ w) {
    __shared__ float tile[64][65];
    const int b   = blockIdx.x;
    const int p   = b >> 12;
    const int rem = b & 4095;
    const int ib  = rem >> 6, ob = rem & 63;
    const int t   = threadIdx.x;
    const size_t plane = (size_t)p * DIN * DOUT;

    {   // load 64(i) x 64(o) tile, float4 over o
        const int o4 = (t & 15) << 2;
        const int r0 = t >> 4;
#pragma unroll
        for (int pass = 0; pass < 4; ++pass) {
            const int r = (pass << 4) + r0;
            const size_t off = plane + (size_t)(ib * 64 + r) * DOUT + ob * 64 + o4;
            const float4 a = *(const float4*)(wp + off);
            const float4 c = *(const float4*)(wn + off);
            tile[r][o4 + 0] = a.x - c.x;
            tile[r][o4 + 1] = a.y - c.y;
            tile[r][o4 + 2] = a.z - c.z;
            tile[r][o4 + 3] = a.w - c.w;
        }
    }
    __syncthreads();
    // store: each wave handles one o-column per pass -> 128B coalesced u16 stores
    const int lane = t & 63, w4 = t >> 6;
#pragma unroll
    for (int pass = 0; pass < 16; ++pass) {
        const int o = (pass << 2) + w4;
        float d = tile[lane][o];
        uint32_t db = __float_as_uint(d);
        uint32_t hb = (db + 0x7fffu + ((db >> 16) & 1u)) & 0xffff0000u;   // RNE bf16
        float l = d - __uint_as_float(hb);                                 // exact
        uint32_t lb = __float_as_uint(l);
        u16 lo16 = (u16)((lb + 0x7fffu + ((lb >> 16) & 1u)) >> 16);
        size_t base = (size_t)(ob * 64 + o) * 24576 + (size_t)p * 8192 + ib * 64 + lane;
        w[base] = (u16)(hb >> 16);
        w[base + 4096] = lo16;
    }
}

// ---------------- Kernel 3: K''=24576 super-GEMM + ADC fold + bias -------------------
// BM=256 BN=128 BK=64; 8 waves (4M x 2N), wave tile 64x64; triple-buffered LDS;
// counted vmcnt(6) pipeline (2 K-tiles in flight), 1 barrier per K-tile.
__global__ __launch_bounds__(512, 2) void gemm_kernel(
    const u16* __restrict__ A,      // [8192][4096] bf16
    const u16* __restrict__ W,      // [4096][24576] bf16
    const float* __restrict__ bias, // [4096]
    float* __restrict__ out)        // [8192][4096] f32
{
    __shared__ __align__(16) char lds[147456];   // A: 3x32K @0 | B: 3x16K @98304

    // XCD swizzle (1024 blocks, bijective): localize B panels per XCD
    const int bid = blockIdx.x;
    const int g   = ((bid & 7) << 7) | (bid >> 3);
    const int mblk = g & 31, nblk = g >> 5;
    const int row0 = mblk << 8, col0 = nblk << 7;

    const int tid = threadIdx.x;
    const int lane = tid & 63, wid = tid >> 6;
    const int wm = wid & 3, wn = wid >> 2;

    // staging: thread t -> row (t>>3) within 64-row round, chunk t&7, swizzled source
    const int swzb = (((tid & 7) ^ ((tid >> 3) & 7)) << 4);
    const char* gA = (const char*)A;
    const char* gB = (const char*)W;
    const size_t aRow = (size_t)(row0 + (tid >> 3)) * (DIN * 2) + swzb;
    const size_t bRow = (size_t)(col0 + (tid >> 3)) * (24576 * 2) + swzb;
    const int dstL = wid << 10;                  // wave-uniform LDS dest base offset

    // fragment read offsets (row&7 == lane&7)
    const int offK0 = (((lane >> 4) + 0) ^ (lane & 7)) << 4;
    const int offK1 = (((lane >> 4) + 4) ^ (lane & 7)) << 4;
    const int aRdRow = ((wm << 6) + (lane & 15)) << 7;
    const int bRdRow = ((wn << 6) + (lane & 15)) << 7;

    f32x4 acc[4][4], fin[4][4];
#pragma unroll
    for (int i = 0; i < 4; ++i)
#pragma unroll
        for (int j = 0; j < 4; ++j) {
            acc[i][j] = (f32x4){0.f, 0.f, 0.f, 0.f};
            fin[i][j] = (f32x4){0.f, 0.f, 0.f, 0.f};
        }

    auto stage = [&](int tile, int part, int buf) {
        const size_t kB = (size_t)tile << 7;
        const size_t kA = (size_t)((tile & 63) << 7);
        char* la = lds + (buf << 15) + dstL;
        char* lb = lds + 98304 + (buf << 14) + dstL;
        if (part == 0) {
            GL(gA + aRow + kA,           la);
            GL(gA + aRow + kA + 524288,  la + 8192);
            GL(gB + bRow + kB,           lb);
        } else {
            GL(gA + aRow + kA + 1048576, la + 16384);
            GL(gA + aRow + kA + 1572864, la + 24576);
            GL(gB + bRow + kB + 3145728, lb + 8192);
        }
    };

    auto phase = [&](int aBuf, int bBuf, int offK, int stTile, int stPart, int stBuf,
                     bool doStage) {
        bf16x8 av[4], bv[4];
        const char* la = lds + aBuf + aRdRow + offK;
        const char* lb = lds + bBuf + bRdRow + offK;
#pragma unroll
        for (int mi = 0; mi < 4; ++mi) av[mi] = *(const bf16x8*)(la + (mi << 11));
#pragma unroll
        for (int ni = 0; ni < 4; ++ni) bv[ni] = *(const bf16x8*)(lb + (ni << 11));
        if (doStage) stage(stTile, stPart, stBuf);
        asm volatile("s_waitcnt lgkmcnt(0)" ::: "memory");
        __builtin_amdgcn_sched_barrier(0);
        __builtin_amdgcn_s_setprio(1);
#pragma unroll
        for (int mi = 0; mi < 4; ++mi)
#pragma unroll
            for (int ni = 0; ni < 4; ++ni)
                acc[mi][ni] = __builtin_amdgcn_mfma_f32_16x16x32_bf16(
                    av[mi], bv[ni], acc[mi][ni], 0, 0, 0);
        __builtin_amdgcn_s_setprio(0);
    };

    // prologue: tiles 0 -> buf0, 1 -> buf1 (12 loads), wait oldest 6, sync
    stage(0, 0, 0); stage(0, 1, 0);
    stage(1, 0, 1); stage(1, 1, 1);
    asm volatile("s_waitcnt vmcnt(6)" ::: "memory");
    __builtin_amdgcn_s_barrier();

    int bufc = 0;
    for (int kt = 0; kt < 384; ++kt) {
        const int nxt  = bufc ? bufc - 1 : 2;            // (bufc+2)%3
        const int aBuf = bufc << 15;
        const int bBuf = 98304 + (bufc << 14);
        const bool st  = (kt < 382);
        phase(aBuf, bBuf, offK0, kt + 2, 0, nxt, st);
        phase(aBuf, bBuf, offK1, kt + 2, 1, nxt, st);
        if ((kt & 127) == 127) {                         // plane boundary: ADC fold
            const float sh = (kt < 128) ? 4.f : (kt < 256) ? 2.f : 1.f;
#pragma unroll
            for (int mi = 0; mi < 4; ++mi)
#pragma unroll
                for (int ni = 0; ni < 4; ++ni)
#pragma unroll
                    for (int r = 0; r < 4; ++r) {
                        float q = rintf(acc[mi][ni][r] * ADC_MUL) * INV256;
                        q = fminf(16.0f, fmaxf(-16.0f, q));
                        fin[mi][ni][r] += sh * q;
                        acc[mi][ni][r] = 0.f;
                    }
        }
        if (st) { asm volatile("s_waitcnt vmcnt(6)" ::: "memory"); }
        else    { asm volatile("s_waitcnt vmcnt(0)" ::: "memory"); }
        __builtin_amdgcn_s_barrier();
        bufc = (bufc == 2) ? 0 : bufc + 1;
    }

    // epilogue: out = fin * 0.01 + bias  (C/D: col=lane&15, row=(lane>>4)*4+r)
    const int orow0 = row0 + (wm << 6) + ((lane >> 4) << 2);
    const int ocol0 = col0 + (wn << 6) + (lane & 15);
#pragma unroll
    for (int ni = 0; ni < 4; ++ni) {
        const int c = ocol0 + (ni << 4);
        const float bv = bias[c];
#pragma unroll
        for (int mi = 0; mi < 4; ++mi)
#pragma unroll
            for (int r = 0; r < 4; ++r)
                out[(size_t)(orow0 + (mi << 4) + r) * DOUT + c] = fin[mi][ni][r] * 0.01f + bv;
    }
}

extern "C" void kernel_launch(void* const* d_in, const int* in_sizes, int n_in,
                              void* d_out, int out_size, void* d_ws, size_t ws_size,
                              hipStream_t stream) {
    const float* x    = (const float*)d_in[0];
    const float* wp   = (const float*)d_in[1];
    const float* wn   = (const float*)d_in[2];
    const float* bias = (const float*)d_in[3];
    float* out = (float*)d_out;

    u16* A = (u16*)d_ws;                          // 8192*4096 bf16 = 67 MB
    u16* W = A + (size_t)TOK * DIN;               // 4096*24576 bf16 = 201 MB

    dac_kernel<<<dim3(4096), dim3(256), 0, stream>>>(x, A);
    wsplit_kernel<<<dim3(NPL * 64 * 64), dim3(256), 0, stream>>>(wp, wn, W);
    gemm_kernel<<<dim3(1024), dim3(512), 0, stream>>>(A, W, bias, out);
}

// Round 8
// 1861.342 us; speedup vs baseline: 1.2181x; 1.2181x over previous
//
#include <hip/hip_runtime.h>
#include <hip/hip_bf16.h>
#include <stdint.h>

#define TOK  8192
#define DIN  4096
#define DOUT 4096
#define NPL  3

typedef unsigned short u16;
typedef __attribute__((ext_vector_type(8))) __bf16 bf16x8;
typedef __attribute__((ext_vector_type(4))) float f32x4;
typedef __attribute__((ext_vector_type(4))) unsigned short u16x4;

// ADC_MUL = (0.6/127) * 8020 * 256
#define ADC_MUL   9699.7795275590551f
#define INV256    0.00390625f

#define GL(src, dst) __builtin_amdgcn_global_load_lds( \
    (const __attribute__((address_space(1))) void*)(src), \
    (__attribute__((address_space(3))) void*)(dst), 16, 0, 0)

// ---------------- Kernel 1: DAC  x (f32) -> k (bf16 integer levels) ----------------
__global__ void dac_kernel(const float* __restrict__ x, u16* __restrict__ a) {
    const int n4 = TOK * DIN / 4;
    int i = blockIdx.x * blockDim.x + threadIdx.x;
    const int stride = gridDim.x * blockDim.x;
    const float4* xv = (const float4*)x;
    u16x4* av = (u16x4*)a;
    for (; i < n4; i += stride) {
        float4 v = xv[i];
        u16x4 o;
        float t, k;
        t = v.x * 0.15f; t = fminf(1.0f, fmaxf(-1.0f, t)); k = rintf(t * 127.0f);
        o.x = (u16)(__float_as_uint(k) >> 16);
        t = v.y * 0.15f; t = fminf(1.0f, fmaxf(-1.0f, t)); k = rintf(t * 127.0f);
        o.y = (u16)(__float_as_uint(k) >> 16);
        t = v.z * 0.15f; t = fminf(1.0f, fmaxf(-1.0f, t)); k = rintf(t * 127.0f);
        o.z = (u16)(__float_as_uint(k) >> 16);
        t = v.w * 0.15f; t = fminf(1.0f, fmaxf(-1.0f, t)); k = rintf(t * 127.0f);
        o.w = (u16)(__float_as_uint(k) >> 16);
        av[i] = o;
    }
}

// -------- Kernel 2: w_eff -> hi/lo bf16, layout W[o][p][kc][hi 64 | lo 64] ----------
// K'' element index = o*24576 + p*8192 + kc*128 + half*64 + (k&63),  kc = k>>6
__global__ void wsplit_kernel(const float* __restrict__ wp, const float* __restrict__ wn,
                              u16* __restrict__ w) {
    __shared__ float tile[64][65];
    const int b   = blockIdx.x;
    const int p   = b >> 12;
    const int rem = b & 4095;
    const int ib  = rem >> 6, ob = rem & 63;      // ib = kc chunk, ob = o-block
    const int t   = threadIdx.x;
    const size_t plane = (size_t)p * DIN * DOUT;

    {   // load 64(i) x 64(o) tile, float4 over o
        const int o4 = (t & 15) << 2;
        const int r0 = t >> 4;
#pragma unroll
        for (int pass = 0; pass < 4; ++pass) {
            const int r = (pass << 4) + r0;
            const size_t off = plane + (size_t)(ib * 64 + r) * DOUT + ob * 64 + o4;
            const float4 a = *(const float4*)(wp + off);
            const float4 c = *(const float4*)(wn + off);
            tile[r][o4 + 0] = a.x - c.x;
            tile[r][o4 + 1] = a.y - c.y;
            tile[r][o4 + 2] = a.z - c.z;
            tile[r][o4 + 3] = a.w - c.w;
        }
    }
    __syncthreads();
    const int lane = t & 63, w4 = t >> 6;
#pragma unroll
    for (int pass = 0; pass < 16; ++pass) {
        const int o = (pass << 2) + w4;
        float d = tile[lane][o];
        uint32_t db = __float_as_uint(d);
        uint32_t hb = (db + 0x7fffu + ((db >> 16) & 1u)) & 0xffff0000u;   // RNE bf16
        float l = d - __uint_as_float(hb);                                 // exact
        uint32_t lb = __float_as_uint(l);
        u16 lo16 = (u16)((lb + 0x7fffu + ((lb >> 16) & 1u)) >> 16);
        size_t base = (size_t)(ob * 64 + o) * 24576 + (size_t)p * 8192 + ib * 128 + lane;
        w[base]      = (u16)(hb >> 16);
        w[base + 64] = lo16;
    }
}

// ---------------- Kernel 3: 8-phase-per-2-K-tiles GEMM + ADC fold + bias -------------
// BM=256 BN=128 BK(A-chunk)=64 feeding hi+lo tiles; 8 waves (4M x 2N), wave 64x64.
// Double-buffered LDS 128 KiB; counted vmcnt(4)/vmcnt(2); A-frags held across phases.
#define PHASE(AREG, BOFF, KOFF, STAGE_STMT, WAIT_STMT)                                  \
    {                                                                                   \
        bf16x8 bR[4];                                                                   \
        _Pragma("unroll")                                                               \
        for (int ni = 0; ni < 4; ++ni)                                                  \
            bR[ni] = *(const bf16x8*)(lB + (BOFF) + bRd + (ni << 11) + (KOFF));         \
        STAGE_STMT;                                                                     \
        __builtin_amdgcn_s_barrier();                                                   \
        asm volatile("s_waitcnt lgkmcnt(0)" ::: "memory");                              \
        __builtin_amdgcn_sched_barrier(0);                                              \
        __builtin_amdgcn_s_setprio(1);                                                  \
        _Pragma("unroll")                                                               \
        for (int mi = 0; mi < 4; ++mi)                                                  \
            _Pragma("unroll")                                                           \
            for (int ni = 0; ni < 4; ++ni)                                              \
                acc[mi][ni] = __builtin_amdgcn_mfma_f32_16x16x32_bf16(                  \
                    AREG[mi], bR[ni], acc[mi][ni], 0, 0, 0);                            \
        __builtin_amdgcn_s_setprio(0);                                                  \
        WAIT_STMT;                                                                      \
        __builtin_amdgcn_s_barrier();                                                   \
    }

__global__ __launch_bounds__(512, 2) void gemm_kernel(
    const u16* __restrict__ A,      // [8192][4096] bf16
    const u16* __restrict__ W,      // [4096][24576] bf16, [o][p][kc][hi64|lo64]
    const float* __restrict__ bias, // [4096]
    float* __restrict__ out)        // [8192][4096] f32
{
    __shared__ __align__(16) char lds[131072];
    // A buf0 @0, buf1 @32768 (256r x 128B) ; B buf0 @65536, buf1 @98304 (hi 16K | lo 16K)

    const int bid = blockIdx.x;                   // 1024 blocks, 1024%8==0 -> bijective
    const int g   = ((bid & 7) << 7) | (bid >> 3);
    const int mblk = g & 31, nblk = g >> 5;
    const int row0 = mblk << 8, col0 = nblk << 7;

    const int tid = threadIdx.x, lane = tid & 63, wid = tid >> 6;
    const int wm = wid >> 1, wn = wid & 1;        // 4 M-groups x 2 N-groups of 64

    const int swzb = (((tid & 7) ^ ((tid >> 3) & 7)) << 4);
    const char* gA = (const char*)A;
    const char* gB = (const char*)W;
    const size_t aRow = (size_t)(row0 + (tid >> 3)) * 8192 + swzb;   // A row = 8192 B
    const size_t bRow = (size_t)(col0 + (tid >> 3)) * 49152 + swzb;  // W row = 49152 B
    const int dstL = wid << 10;

    const int koff0 = (((lane >> 4) + 0) ^ (lane & 7)) << 4;
    const int koff1 = (((lane >> 4) + 4) ^ (lane & 7)) << 4;
    const int aRd = ((wm << 6) + (lane & 15)) << 7;
    const int bRd = ((wn << 6) + (lane & 15)) << 7;

    f32x4 acc[4][4], fin[4][4];
#pragma unroll
    for (int i = 0; i < 4; ++i)
#pragma unroll
        for (int j = 0; j < 4; ++j) {
            acc[i][j] = (f32x4){0.f, 0.f, 0.f, 0.f};
            fin[i][j] = (f32x4){0.f, 0.f, 0.f, 0.f};
        }

    auto stageA = [&](int it1, int j, char* dst) {   // j-th 64-row slab of A chunk
        GL(gA + aRow + ((size_t)j << 19) + ((size_t)(it1 & 63) << 7),
           dst + (j << 13) + dstL);
    };
    auto stageBhi = [&](int it1, int j, char* dst) { // j-th 64-row slab, hi half
        GL(gB + bRow + (size_t)it1 * 256 + ((size_t)j << 6) * 49152,
           dst + (j << 13) + dstL);
    };
    auto stageBlo = [&](int it1, int j, char* dst) { // lo half (+128 B in source row)
        GL(gB + bRow + (size_t)it1 * 256 + 128 + ((size_t)j << 6) * 49152,
           dst + 16384 + (j << 13) + dstL);
    };

    // prologue: stage iteration 0 into buf0; drain A+Bhi (6 oldest), keep Blo in flight
    {
        char* a0 = lds;
        char* b0 = lds + 65536;
        stageA(0, 0, a0); stageA(0, 1, a0); stageA(0, 2, a0); stageA(0, 3, a0);
        stageBhi(0, 0, b0); stageBhi(0, 1, b0);
        stageBlo(0, 0, b0); stageBlo(0, 1, b0);
        asm volatile("s_waitcnt vmcnt(2)" ::: "memory");
        __builtin_amdgcn_s_barrier();
    }

    for (int it = 0; it < 192; ++it) {
        const int buf = it & 1;
        const char* lA = lds + (buf << 15);
        const char* lB = lds + 65536 + (buf << 15);
        char* sA1 = lds + ((buf ^ 1) << 15);
        char* sB1 = lds + 65536 + ((buf ^ 1) << 15);
        const bool st = (it < 191);

        bf16x8 aR0[4], aR1[4];
#pragma unroll
        for (int mi = 0; mi < 4; ++mi)
            aR0[mi] = *(const bf16x8*)(lA + aRd + (mi << 11) + koff0);
#pragma unroll
        for (int mi = 0; mi < 4; ++mi)
            aR1[mi] = *(const bf16x8*)(lA + aRd + (mi << 11) + koff1);

        // ph0: hi ks0   (stage next A slabs 0,1)
        PHASE(aR0, 0, koff0,
              { if (st) { stageA(it + 1, 0, sA1); stageA(it + 1, 1, sA1); } }, {});
        // ph1: hi ks1   (stage next A slabs 2,3; drain THIS iter's Blo)
        PHASE(aR1, 0, koff1,
              { if (st) { stageA(it + 1, 2, sA1); stageA(it + 1, 3, sA1); } },
              { if (st) asm volatile("s_waitcnt vmcnt(4)" ::: "memory");
                else    asm volatile("s_waitcnt vmcnt(0)" ::: "memory"); });
        // ph2: lo ks0   (stage next Bhi)
        PHASE(aR0, 16384, koff0,
              { if (st) { stageBhi(it + 1, 0, sB1); stageBhi(it + 1, 1, sB1); } }, {});
        // ph3: lo ks1   (stage next Blo; drain next iter's A+Bhi, keep its Blo)
        PHASE(aR1, 16384, koff1,
              { if (st) { stageBlo(it + 1, 0, sB1); stageBlo(it + 1, 1, sB1); } },
              { if (st) asm volatile("s_waitcnt vmcnt(2)" ::: "memory");
                else    asm volatile("s_waitcnt vmcnt(0)" ::: "memory"); });

        if ((it & 63) == 63) {                        // plane boundary: ADC fold
            const float sh = (it == 63) ? 4.f : (it == 127) ? 2.f : 1.f;
#pragma unroll
            for (int mi = 0; mi < 4; ++mi)
#pragma unroll
                for (int ni = 0; ni < 4; ++ni)
#pragma unroll
                    for (int r = 0; r < 4; ++r) {
                        float q = rintf(acc[mi][ni][r] * ADC_MUL) * INV256;
                        q = fminf(16.0f, fmaxf(-16.0f, q));
                        fin[mi][ni][r] += sh * q;
                        acc[mi][ni][r] = 0.f;
                    }
        }
    }

    // epilogue: out = fin * 0.01 + bias  (C/D: col=lane&15, row=(lane>>4)*4+r)
    const int orow0 = row0 + (wm << 6) + ((lane >> 4) << 2);
    const int ocol0 = col0 + (wn << 6) + (lane & 15);
#pragma unroll
    for (int ni = 0; ni < 4; ++ni) {
        const int c = ocol0 + (ni << 4);
        const float bv = bias[c];
#pragma unroll
        for (int mi = 0; mi < 4; ++mi)
#pragma unroll
            for (int r = 0; r < 4; ++r)
                out[(size_t)(orow0 + (mi << 4) + r) * DOUT + c] = fin[mi][ni][r] * 0.01f + bv;
    }
}

extern "C" void kernel_launch(void* const* d_in, const int* in_sizes, int n_in,
                              void* d_out, int out_size, void* d_ws, size_t ws_size,
                              hipStream_t stream) {
    const float* x    = (const float*)d_in[0];
    const float* wp   = (const float*)d_in[1];
    const float* wn   = (const float*)d_in[2];
    const float* bias = (const float*)d_in[3];
    float* out = (float*)d_out;

    u16* A = (u16*)d_ws;                          // 8192*4096 bf16 = 67 MB
    u16* W = A + (size_t)TOK * DIN;               // 4096*24576 bf16 = 201 MB

    dac_kernel<<<dim3(4096), dim3(256), 0, stream>>>(x, A);
    wsplit_kernel<<<dim3(NPL * 64 * 64), dim3(256), 0, stream>>>(wp, wn, W);
    gemm_kernel<<<dim3(1024), dim3(512), 0, stream>>>(A, W, bias, out);
}